// Round 1
// baseline (202.679 us; speedup 1.0000x reference)
//
#include <hip/hip_runtime.h>
#include <math.h>

// Problem constants
#define BSZ 65536
#define NC 10
#define T 8
#define NE 128
#define EMB 256
#define ZD 128
#define NCT 80   // NC*T
#define CCF 0.25f
#define BB 32    // batch rows per block in main kernel

// Workspace layout (float offsets)
#define W_OFF   0        // 128*80 fused weight W = mu_w @ fc_w, row-major [d][k]
#define B2_OFF  10240    // 128 fused bias b2 = mu_w @ fc_b + mu_b
#define CN_OFF  10368    // 128 codebook squared norms
#define CT_OFF  10496    // 128 histogram counts (unsigned)
#define SQ_OFF  10624    // 1 float: sum of valid squared errors

// ---------------------------------------------------------------------------
// Prep: fold fc+mu into one matrix, codebook norms, zero accumulators.
// Blocks 0..127: W row d + b2[d]. Block 128: cnorm + zero counts/sqerr.
// ---------------------------------------------------------------------------
__global__ __launch_bounds__(128) void prep_kernel(
    const float* __restrict__ codebook, const float* __restrict__ fc_w,
    const float* __restrict__ fc_b, const float* __restrict__ mu_w,
    const float* __restrict__ mu_b, float* __restrict__ ws)
{
  const int d = blockIdx.x;
  const int tid = threadIdx.x;
  if (d < ZD) {
    __shared__ float mrow[EMB];
    mrow[tid]       = mu_w[d * EMB + tid];
    mrow[tid + 128] = mu_w[d * EMB + tid + 128];
    __syncthreads();
    if (tid < NCT) {
      float acc = 0.f;
      for (int e = 0; e < EMB; ++e) acc = fmaf(mrow[e], fc_w[e * NCT + tid], acc);
      ws[W_OFF + d * NCT + tid] = acc;
    } else if (tid == NCT) {
      float acc = mu_b[d];
      for (int e = 0; e < EMB; ++e) acc = fmaf(mrow[e], fc_b[e], acc);
      ws[B2_OFF + d] = acc;
    }
  } else {
    if (tid < NE) {
      float s = 0.f;
      for (int c = 0; c < NC; ++c) { float v = codebook[tid * NC + c]; s = fmaf(v, v, s); }
      ws[CN_OFF + tid] = s;
      ((unsigned*)ws)[CT_OFF + tid] = 0u;
    }
    if (tid == 0) ws[SQ_OFF] = 0.f;
  }
}

// ---------------------------------------------------------------------------
// Main fused kernel: conv -> VQ -> straight-through zf -> fused GEMM -> out.
// Block: 256 threads, BB=32 batch rows (one thread per (b,t) in VQ stage).
// ---------------------------------------------------------------------------
__global__ __launch_bounds__(256, 2) void main_kernel(
    const float* __restrict__ fn, const unsigned char* __restrict__ mask,
    const float* __restrict__ conv_w, const float* __restrict__ conv_b,
    const float* __restrict__ codebook, float* __restrict__ ws,
    float* __restrict__ out)
{
  // LDS: W rows padded to 84 (odd*4 pad -> conflict-free float4 reads with
  // d = dgrp + 8j lane mapping); zf rows padded to 84 likewise; codebook rows
  // padded to 12 for aligned b128+b128+b64 broadcast loads.
  __shared__ __align__(16) float Wl[ZD * 84];     // 43008 B (reused as store stage)
  __shared__ __align__(16) float zfl[BB * 84];    // 10752 B
  __shared__ __align__(16) float cbp[NE * 12];    //  6144 B
  __shared__ float cnl[NE];                       //   512 B
  __shared__ float b2l[ZD];                       //   512 B
  __shared__ float cwl[NC * 4];                   //   160 B
  __shared__ float cbb[NC];                       //    40 B
  __shared__ unsigned hist[NE];                   //   512 B
  __shared__ float sqacc;

  const int tid = threadIdx.x;

  // ---- cooperative LDS fill ----
  for (int i = tid; i < ZD * NCT; i += 256) {
    int dd = i / NCT, kk = i - dd * NCT;
    Wl[dd * 84 + kk] = ws[W_OFF + i];
  }
  for (int i = tid; i < NE * NC; i += 256) {
    int e = i / NC, c = i - e * NC;
    cbp[e * 12 + c] = codebook[i];
  }
  if (tid < NE) { cnl[tid] = ws[CN_OFF + tid]; b2l[tid] = ws[B2_OFF + tid]; hist[tid] = 0u; }
  if (tid < NC * 4) cwl[tid] = conv_w[tid];
  if (tid >= 64 && tid < 64 + NC) cbb[tid - 64] = conv_b[tid - 64];
  if (tid == 255) sqacc = 0.f;
  __syncthreads();

  // ---- stage 1: conv + VQ, one (b,t) position per thread ----
  const int t = tid & 7, bl = tid >> 3;
  const int b = blockIdx.x * BB + bl;

  const float4 p = ((const float4*)fn)[b * T + t];   // fn[b, t*4 .. t*4+3]
  float z[NC];
#pragma unroll
  for (int c = 0; c < NC; ++c) {
    float pre = fmaf(p.w, cwl[c * 4 + 3],
                fmaf(p.z, cwl[c * 4 + 2],
                fmaf(p.y, cwl[c * 4 + 1], p.x * cwl[c * 4 + 0]))) + cbb[c];
    z[c] = pre > 0.f ? pre : 0.f;
  }
  float znorm = 0.f;
#pragma unroll
  for (int c = 0; c < NC; ++c) znorm = fmaf(z[c], z[c], znorm);

  // argmin over 128 codebook entries, tracking top-2 for fp64 tie refinement
  float best = 3.4e38f, best2 = 3.4e38f;
  int bi = 0, bi2 = 0;
#pragma unroll 4
  for (int e = 0; e < NE; ++e) {
    const float4 c0 = *(const float4*)&cbp[e * 12];
    const float4 c1 = *(const float4*)&cbp[e * 12 + 4];
    const float2 c2 = *(const float2*)&cbp[e * 12 + 8];
    float dot = z[0] * c0.x;
    dot = fmaf(z[1], c0.y, dot); dot = fmaf(z[2], c0.z, dot); dot = fmaf(z[3], c0.w, dot);
    dot = fmaf(z[4], c1.x, dot); dot = fmaf(z[5], c1.y, dot); dot = fmaf(z[6], c1.z, dot);
    dot = fmaf(z[7], c1.w, dot); dot = fmaf(z[8], c2.x, dot); dot = fmaf(z[9], c2.y, dot);
    float dd = (znorm - 2.0f * dot) + cnl[e];   // mirrors reference expansion
    if (dd < best)       { best2 = best; bi2 = bi; best = dd; bi = e; }
    else if (dd < best2) { best2 = dd; bi2 = e; }
  }
  // near-tie: resolve in fp64 (rare divergent path) to match reference argmin
  if (best2 - best < 1e-3f * (fabsf(best) + 1.0f)) {
    double s1 = 0.0, s2 = 0.0;
    for (int c = 0; c < NC; ++c) {
      double zc = (double)z[c];
      double a = zc - (double)cbp[bi * 12 + c];  s1 += a * a;
      double q = zc - (double)cbp[bi2 * 12 + c]; s2 += q * q;
    }
    if (s2 < s1 || (s2 == s1 && bi2 < bi)) bi = bi2;
  }

  // straight-through output + squared error; zf[b][c*8+t] = q_st (permuted layout)
  float sq = 0.f;
#pragma unroll
  for (int c = 0; c < NC; ++c) {
    float qc = cbp[bi * 12 + c];
    float df = qc - z[c];
    sq = fmaf(df, df, sq);
    zfl[bl * 84 + c * 8 + t] = z[c] + df;   // z + (q - z), matches reference
  }

  const bool valid = (mask[b] == 0);
  float sv = valid ? sq : 0.f;
#pragma unroll
  for (int off = 32; off > 0; off >>= 1) sv += __shfl_down(sv, off);
  if ((tid & 63) == 0) atomicAdd(&sqacc, sv);
  if (valid) atomicAdd(&hist[bi], 1u);
  __syncthreads();

  // ---- stage 2: out[b,:] = zf[b,:] @ W^T + b2 ----
  // thread -> (bl2 = tid>>3, dgrp = tid&7), computes d = dgrp + 8j, j=0..15
  const int dg = tid & 7;
  const int bl2 = tid >> 3;
  float acc[16];
#pragma unroll
  for (int j = 0; j < 16; ++j) acc[j] = 0.f;
#pragma unroll 2
  for (int k4 = 0; k4 < 20; ++k4) {
    const float4 zv = *(const float4*)&zfl[bl2 * 84 + k4 * 4];  // broadcast over dg lanes
#pragma unroll
    for (int j = 0; j < 16; ++j) {
      const float4 wv = *(const float4*)&Wl[(dg + 8 * j) * 84 + k4 * 4];
      acc[j] = fmaf(zv.x, wv.x, acc[j]);
      acc[j] = fmaf(zv.y, wv.y, acc[j]);
      acc[j] = fmaf(zv.z, wv.z, acc[j]);
      acc[j] = fmaf(zv.w, wv.w, acc[j]);
    }
  }
  __syncthreads();                 // everyone done reading Wl/zfl
  // stage results in (reused) Wl for fully coalesced global stores
  float* stage = Wl;               // needs 32*132 = 4224 floats
#pragma unroll
  for (int j = 0; j < 16; ++j) {
    int d = dg + 8 * j;
    stage[bl2 * 132 + d] = acc[j] + b2l[d];
  }
  __syncthreads();
  for (int r = 0; r < 4; ++r) {
    int lin = r * 256 + tid;       // float4 index within 32x128 tile (1024 total)
    int row = lin >> 5;            // 32 float4 per output row
    int q4 = lin & 31;
    float4 v = *(const float4*)&stage[row * 132 + q4 * 4];
    ((float4*)out)[(blockIdx.x * BB + row) * 32 + q4] = v;
  }

  // ---- global accumulation ----
  if (tid == 0) atomicAdd(&ws[SQ_OFF], sqacc);
  if (tid < NE) { unsigned h = hist[tid]; if (h) atomicAdd(&((unsigned*)ws)[CT_OFF + tid], h); }
}

// ---------------------------------------------------------------------------
// Finalize: cmt_loss and perplexity scalars.
// ---------------------------------------------------------------------------
__global__ __launch_bounds__(128) void fin_kernel(const float* __restrict__ ws,
                                                  float* __restrict__ out)
{
  __shared__ float red[NE];
  const int tid = threadIdx.x;
  const unsigned c = ((const unsigned*)ws)[CT_OFF + tid];
  const float cf = (float)c;
  red[tid] = cf;
  __syncthreads();
  for (int s = 64; s > 0; s >>= 1) { if (tid < s) red[tid] += red[tid + s]; __syncthreads(); }
  const float vfsum = red[0];
  __syncthreads();
  const float pr = cf / vfsum;
  red[tid] = pr * logf(pr + 1e-10f);
  __syncthreads();
  for (int s = 64; s > 0; s >>= 1) { if (tid < s) red[tid] += red[tid + s]; __syncthreads(); }
  if (tid == 0) {
    const float ent = red[0];
    const float e_latent = ws[SQ_OFF] / (vfsum * (float)NC);
    out[(size_t)BSZ * ZD + 0] = CCF * e_latent;   // cmt_loss
    out[(size_t)BSZ * ZD + 1] = expf(-ent);       // perplexity
  }
}

// ---------------------------------------------------------------------------
extern "C" void kernel_launch(void* const* d_in, const int* in_sizes, int n_in,
                              void* d_out, int out_size, void* d_ws, size_t ws_size,
                              hipStream_t stream)
{
  const float* fn            = (const float*)d_in[0];
  const unsigned char* mask  = (const unsigned char*)d_in[1];  // bool array (all-false in test)
  const float* conv_w        = (const float*)d_in[2];
  const float* conv_b        = (const float*)d_in[3];
  const float* codebook      = (const float*)d_in[4];
  const float* fc_w          = (const float*)d_in[5];
  const float* fc_b          = (const float*)d_in[6];
  const float* mu_w          = (const float*)d_in[7];
  const float* mu_b          = (const float*)d_in[8];
  float* out = (float*)d_out;
  float* ws  = (float*)d_ws;

  hipLaunchKernelGGL(prep_kernel, dim3(ZD + 1), dim3(128), 0, stream,
                     codebook, fc_w, fc_b, mu_w, mu_b, ws);
  hipLaunchKernelGGL(main_kernel, dim3(BSZ / BB), dim3(256), 0, stream,
                     fn, mask, conv_w, conv_b, codebook, ws, out);
  hipLaunchKernelGGL(fin_kernel, dim3(1), dim3(128), 0, stream, ws, out);
}

// Round 2
// 160.661 us; speedup vs baseline: 1.2615x; 1.2615x over previous
//
#include <hip/hip_runtime.h>
#include <math.h>

#define BSZ 65536
#define NC 10
#define T 8
#define NE 128
#define EMB 256
#define ZD 128
#define NCT 80
#define KP 96          // K padded to 96 for 3x mfma_16x16x32
#define CCF 0.25f
#define BB 32
#define ZPAD 104       // zf16 LDS row pitch in halves (208 B, 16B-aligned, conflict-free)

// ws float offsets
#define B2_OFF 6144    // floats 0..6143 = Wh f16[128][96]
#define NC_OFF 6272    // negated codebook fp32 [128][12]: 0-9=-c, 10=cn/2, 11=pad
#define CT_OFF 7808    // 128 u32 histogram
#define SQ_OFF 7936    // 1 float sq-err accumulator

typedef _Float16 half8 __attribute__((ext_vector_type(8)));
typedef float f32x4 __attribute__((ext_vector_type(4)));

// ---------------------------------------------------------------------------
// Prep: W = mu_w@fc_w -> f16 [128][96]; b2 = mu_w@fc_b + mu_b; negated
// codebook + cn/2; zero accumulators. 2 threads per dot for latency.
// ---------------------------------------------------------------------------
__global__ __launch_bounds__(256) void prep_kernel(
    const float* __restrict__ codebook, const float* __restrict__ fc_w,
    const float* __restrict__ fc_b, const float* __restrict__ mu_w,
    const float* __restrict__ mu_b, float* __restrict__ ws)
{
  const int blk = blockIdx.x, tid = threadIdx.x;
  if (blk < 80) {                       // 80*256/2 = 10240 W elements
    const int gi = blk * 256 + tid;
    const int idx = gi >> 1, h = gi & 1;
    const int d = idx / NCT, k = idx - d * NCT;
    const float* mw = mu_w + d * EMB + h * 128;
    const float* fw = fc_w + (h * 128) * NCT + k;
    float acc = 0.f;
#pragma unroll 8
    for (int e = 0; e < 128; ++e) acc = fmaf(mw[e], fw[e * NCT], acc);
    acc += __shfl_xor(acc, 1);
    if (h == 0) ((_Float16*)ws)[d * KP + k] = (_Float16)acc;
  } else if (blk == 80) {               // b2
    const int d = tid >> 1, h = tid & 1;
    const float* mw = mu_w + d * EMB + h * 128;
    const float* fb = fc_b + h * 128;
    float acc = 0.f;
#pragma unroll 8
    for (int e = 0; e < 128; ++e) acc = fmaf(mw[e], fb[e], acc);
    acc += __shfl_xor(acc, 1);
    if (h == 0) ws[B2_OFF + d] = acc + mu_b[d];
  } else {                              // codebook prep + zeros + W K-tail
    if (tid < NE) {
      float cn = 0.f;
      for (int c = 0; c < NC; ++c) {
        float v = codebook[tid * NC + c];
        ws[NC_OFF + tid * 12 + c] = -v;
        cn = fmaf(v, v, cn);
      }
      ws[NC_OFF + tid * 12 + 10] = 0.5f * cn;
      ws[NC_OFF + tid * 12 + 11] = 0.f;
      ((unsigned*)ws)[CT_OFF + tid] = 0u;
      unsigned* wz = (unsigned*)ws;     // zero Wh halves 80..95 of row tid
      for (int j = 0; j < 8; ++j) wz[tid * 48 + 40 + j] = 0u;
    }
    if (tid == 0) ws[SQ_OFF] = 0.f;
  }
}

// ---------------------------------------------------------------------------
// Main: conv -> VQ argmin (fp32 screen + fp64 tie recheck) -> zf f16 in LDS
// -> out = zf @ W^T + b2 via mfma_f32_16x16x32_f16.
// ---------------------------------------------------------------------------
__global__ __launch_bounds__(256, 4) void main_kernel(
    const float* __restrict__ fn, const unsigned char* __restrict__ mask,
    const float* __restrict__ conv_w, const float* __restrict__ conv_b,
    float* __restrict__ ws, float* __restrict__ out)
{
  __shared__ __align__(16) float ncl[NE * 12];       // 6144 B
  __shared__ __align__(16) _Float16 zfh[BB * ZPAD];  // 6656 B
  __shared__ float b2l[ZD];
  __shared__ float cwl[NC * 4];
  __shared__ float cbb[NC];
  __shared__ unsigned hist[NE];
  __shared__ float sqacc;

  const int tid = threadIdx.x;

  // ---- cooperative fill ----
  {
    const float4* src = (const float4*)(ws + NC_OFF);
    float4* dst = (float4*)ncl;
    for (int i = tid; i < NE * 3; i += 256) dst[i] = src[i];
  }
  if (tid < ZD) b2l[tid] = ws[B2_OFF + tid];
  if (tid < NE) hist[tid] = 0u;
  if (tid >= 128 && tid < 128 + NC * 4) cwl[tid - 128] = conv_w[tid - 128];
  if (tid >= 192 && tid < 192 + NC) cbb[tid - 192] = conv_b[tid - 192];
  if (tid == 255) sqacc = 0.f;
  __syncthreads();

  // ---- stage 1: conv + VQ, one (b,t) per thread ----
  const int t = tid & 7, bl = tid >> 3;
  const int b = blockIdx.x * BB + bl;
  const float4 p = ((const float4*)fn)[b * T + t];
  float z[NC];
#pragma unroll
  for (int c = 0; c < NC; ++c) {
    float pre = fmaf(p.w, cwl[c * 4 + 3], fmaf(p.z, cwl[c * 4 + 2],
                fmaf(p.y, cwl[c * 4 + 1], fmaf(p.x, cwl[c * 4 + 0], cbb[c]))));
    z[c] = pre > 0.f ? pre : 0.f;
  }
  float zn = 0.f;
#pragma unroll
  for (int c = 0; c < NC; ++c) zn = fmaf(z[c], z[c], zn);

  // screen on d' = cn/2 - z.c  (d_ref = 2*d' + zn, monotone)
  float best = 3.4e38f, best2 = 3.4e38f;
  int bi = 0, bi2 = 0;
  const float4* nc4 = (const float4*)ncl;
#pragma unroll 4
  for (int e = 0; e < NE; ++e) {
    const float4 r0 = nc4[e * 3 + 0];
    const float4 r1 = nc4[e * 3 + 1];
    const float4 r2 = nc4[e * 3 + 2];
    float acc = fmaf(z[0], r0.x, r2.z);   // start from cn/2
    acc = fmaf(z[1], r0.y, acc); acc = fmaf(z[2], r0.z, acc);
    acc = fmaf(z[3], r0.w, acc); acc = fmaf(z[4], r1.x, acc);
    acc = fmaf(z[5], r1.y, acc); acc = fmaf(z[6], r1.z, acc);
    acc = fmaf(z[7], r1.w, acc); acc = fmaf(z[8], r2.x, acc);
    acc = fmaf(z[9], r2.y, acc);
    if (acc < best)       { best2 = best; bi2 = bi; best = acc; bi = e; }
    else if (acc < best2) { best2 = acc; bi2 = e; }
  }
  // near-tie: fp64 pair recheck (rare divergent path), matches reference argmin
  if ((best2 - best) * 2.f < 1e-3f * (fabsf(2.f * best + zn) + 1.f)) {
    double s1 = 0.0, s2 = 0.0;
    for (int c = 0; c < NC; ++c) {
      double a = (double)z[c] + (double)ncl[bi * 12 + c];
      double q2 = (double)z[c] + (double)ncl[bi2 * 12 + c];
      s1 += a * a; s2 += q2 * q2;
    }
    if (s2 < s1 || (s2 == s1 && bi2 < bi)) bi = bi2;
  }

  // zf[b][c*8+t] = q (== z + (q-z)); squared error in fp32
  float sq = 0.f;
#pragma unroll
  for (int c = 0; c < NC; ++c) {
    float qc = -ncl[bi * 12 + c];
    float df = qc - z[c];
    sq = fmaf(df, df, sq);
    zfh[bl * ZPAD + c * 8 + t] = (_Float16)qc;
  }
  zfh[bl * ZPAD + 80 + t] = (_Float16)0.f;   // K-pad 80..95
  zfh[bl * ZPAD + 88 + t] = (_Float16)0.f;

  const bool valid = (mask[b] == 0);
  float sv = valid ? sq : 0.f;
#pragma unroll
  for (int off = 32; off > 0; off >>= 1) sv += __shfl_down(sv, off);
  if ((tid & 63) == 0) atomicAdd(&sqacc, sv);
  if (valid) atomicAdd(&hist[bi], 1u);
  __syncthreads();

  // ---- stage 2: out tile 32x128 = zf(32x96) @ Wh^T(96x128) via MFMA ----
  const int lane = tid & 63, w = tid >> 6;
  const int rl = lane & 15, q8 = (lane >> 4) * 8;
  const _Float16* Wh = (const _Float16*)ws;
  const int n0 = w * 32;                    // 2 n-tiles per wave
  f32x4 acc[2][2] = {};
#pragma unroll
  for (int c = 0; c < 3; ++c) {
    half8 a0 = *(const half8*)&zfh[(rl) * ZPAD + c * 32 + q8];
    half8 a1 = *(const half8*)&zfh[(16 + rl) * ZPAD + c * 32 + q8];
    half8 b0 = *(const half8*)&Wh[(n0 + rl) * KP + c * 32 + q8];
    half8 b1 = *(const half8*)&Wh[(n0 + 16 + rl) * KP + c * 32 + q8];
    acc[0][0] = __builtin_amdgcn_mfma_f32_16x16x32_f16(a0, b0, acc[0][0], 0, 0, 0);
    acc[0][1] = __builtin_amdgcn_mfma_f32_16x16x32_f16(a0, b1, acc[0][1], 0, 0, 0);
    acc[1][0] = __builtin_amdgcn_mfma_f32_16x16x32_f16(a1, b0, acc[1][0], 0, 0, 0);
    acc[1][1] = __builtin_amdgcn_mfma_f32_16x16x32_f16(a1, b1, acc[1][1], 0, 0, 0);
  }
  const float bias0 = b2l[n0 + rl], bias1 = b2l[n0 + 16 + rl];
  const int rowb = (lane >> 4) * 4;
  const int bbase = blockIdx.x * BB;
#pragma unroll
  for (int mt = 0; mt < 2; ++mt)
#pragma unroll
    for (int reg = 0; reg < 4; ++reg) {
      const int row = bbase + mt * 16 + rowb + reg;
      out[row * ZD + n0 + rl]      = acc[mt][0][reg] + bias0;
      out[row * ZD + n0 + 16 + rl] = acc[mt][1][reg] + bias1;
    }

  // ---- global accumulation ----
  if (tid == 0) atomicAdd(&ws[SQ_OFF], sqacc);
  if (tid < NE) { unsigned h = hist[tid]; if (h) atomicAdd(&((unsigned*)ws)[CT_OFF + tid], h); }
}

// ---------------------------------------------------------------------------
// Finalize: cmt_loss and perplexity.
// ---------------------------------------------------------------------------
__global__ __launch_bounds__(128) void fin_kernel(const float* __restrict__ ws,
                                                  float* __restrict__ out)
{
  __shared__ float red[NE];
  const int tid = threadIdx.x;
  const unsigned c = ((const unsigned*)ws)[CT_OFF + tid];
  const float cf = (float)c;
  red[tid] = cf;
  __syncthreads();
  for (int s = 64; s > 0; s >>= 1) { if (tid < s) red[tid] += red[tid + s]; __syncthreads(); }
  const float vfsum = red[0];
  __syncthreads();
  const float pr = cf / vfsum;
  red[tid] = pr * logf(pr + 1e-10f);
  __syncthreads();
  for (int s = 64; s > 0; s >>= 1) { if (tid < s) red[tid] += red[tid + s]; __syncthreads(); }
  if (tid == 0) {
    const float ent = red[0];
    const float e_latent = ws[SQ_OFF] / (vfsum * (float)NC);
    out[(size_t)BSZ * ZD + 0] = CCF * e_latent;
    out[(size_t)BSZ * ZD + 1] = expf(-ent);
  }
}

// ---------------------------------------------------------------------------
extern "C" void kernel_launch(void* const* d_in, const int* in_sizes, int n_in,
                              void* d_out, int out_size, void* d_ws, size_t ws_size,
                              hipStream_t stream)
{
  const float* fn           = (const float*)d_in[0];
  const unsigned char* mask = (const unsigned char*)d_in[1];
  const float* conv_w       = (const float*)d_in[2];
  const float* conv_b       = (const float*)d_in[3];
  const float* codebook     = (const float*)d_in[4];
  const float* fc_w         = (const float*)d_in[5];
  const float* fc_b         = (const float*)d_in[6];
  const float* mu_w         = (const float*)d_in[7];
  const float* mu_b         = (const float*)d_in[8];
  float* out = (float*)d_out;
  float* ws  = (float*)d_ws;

  hipLaunchKernelGGL(prep_kernel, dim3(82), dim3(256), 0, stream,
                     codebook, fc_w, fc_b, mu_w, mu_b, ws);
  hipLaunchKernelGGL(main_kernel, dim3(BSZ / BB), dim3(256), 0, stream,
                     fn, mask, conv_w, conv_b, ws, out);
  hipLaunchKernelGGL(fin_kernel, dim3(1), dim3(128), 0, stream, ws, out);
}